// Round 4
// baseline (270.171 us; speedup 1.0000x reference)
//
#include <hip/hip_runtime.h>
#include <cmath>

#define NQ 32
#define H 512
#define NOFF 496
#define NR4 528   // NQ + NOFF
#define NCOL 34   // col 0: activation; 1..32: jacobian; 33: g-network
#define NRB 8
#define NBLK (NCOL * NRB)   // 272

__device__ __forceinline__ float sigmoidf(float x) {
    return 1.0f / (1.0f + __expf(-x));
}
__device__ __forceinline__ float dot4(float4 a, float4 b) {
    return a.x * b.x + a.y * b.y + a.z * b.z + a.w * b.w;
}

__device__ __forceinline__ void release_add(unsigned* p) {
    __hip_atomic_fetch_add(p, 1u, __ATOMIC_RELEASE, __HIP_MEMORY_SCOPE_AGENT);
}
__device__ __forceinline__ void acquire_wait(const unsigned* p, unsigned target) {
    while (__hip_atomic_load(p, __ATOMIC_ACQUIRE, __HIP_MEMORY_SCOPE_AGENT) < target)
        __builtin_amdgcn_s_sleep(1);
}

// 272 blocks x 256 threads, single launch, flag-based pipeline (no grid.sync).
__global__ void __launch_bounds__(256, 4) fused(
    const float* __restrict__ q, const float* __restrict__ q_t, const float* __restrict__ q_tt,
    const float* __restrict__ W1, const float* __restrict__ b1,
    const float* __restrict__ W2, const float* __restrict__ b2,
    const float* __restrict__ W3, const float* __restrict__ b3,
    const float* __restrict__ Wd, const float* __restrict__ bd,
    const float* __restrict__ Wo, const float* __restrict__ bo,
    const float* __restrict__ Wg1, const float* __restrict__ bg1,
    const float* __restrict__ Wg2, const float* __restrict__ bg2,
    const float* __restrict__ Wg3, const float* __restrict__ bg3,
    float* __restrict__ Y, float* __restrict__ Z,
    float* __restrict__ g2, float* __restrict__ gvec,
    float* __restrict__ U,
    unsigned* __restrict__ ready2, unsigned* __restrict__ ready3,
    unsigned* __restrict__ done, float* __restrict__ out)
{
    const int b = blockIdx.x;
    const int c = b >> 3, rb = b & 7;
    const int tid = threadIdx.x;       // 256 threads, 4 waves
    const int lane = tid & 63, wv = tid >> 6;
    const bool isg = (c == 33);

    __shared__ float qs[NQ];
    __shared__ float h1s[H], b1s[H];   // stage-1 output; reused as hv/bv later
    __shared__ float rawv[H];
    // assembly scratch
    __shared__ float ldiag[NQ], loff[NOFF], vv[NR4];
    __shared__ float Lm[NQ][NQ + 1], Dq[NQ][NQ + 1], Fj[NQ][NQ + 1];
    __shared__ float qts[NQ], qtts[NQ], LTq[NQ], t1s[NQ], u2[NQ];
    __shared__ int amLast;

    if (tid < NQ) qs[tid] = q[tid];
    __syncthreads();

    // ---- Stage 1: h1 (or g1) + B1 column, fully per block (cheap) ----
    {
        const float* Wf = isg ? Wg1 : W1;
        const float* bf = isg ? bg1 : b1;
        for (int j = tid; j < H; j += 256) {
            const float4* wr = (const float4*)(Wf + j * NQ);
            float acc = 0.f;
            #pragma unroll
            for (int cc = 0; cc < 8; ++cc) {
                float4 w = wr[cc];
                acc += w.x * qs[4*cc] + w.y * qs[4*cc+1] + w.z * qs[4*cc+2] + w.w * qs[4*cc+3];
            }
            float h = sigmoidf(acc + bf[j]);
            h1s[j] = h;
            b1s[j] = (c == 0 || isg) ? h : h * (1.f - h) * Wf[j * NQ + (c - 1)];
        }
    }
    __syncthreads();

    // ---- Stage 2: 64 rows of layer-2 GEMV for this column ----
    {
        const float4* Wv = (const float4*)(isg ? Wg2 : W2);
        const float4* bvp = (const float4*)b1s;
        float4 v0 = bvp[lane], v1 = bvp[lane + 64];
        int r0 = rb * 64 + wv * 16;
        #pragma unroll 8
        for (int i = 0; i < 16; ++i) {
            int r = r0 + i;
            const float4* wr = Wv + (size_t)r * (H / 4);
            float acc = dot4(wr[lane], v0) + dot4(wr[lane + 64], v1);
            #pragma unroll
            for (int m = 32; m > 0; m >>= 1) acc += __shfl_xor(acc, m, 64);
            if (lane == 0) {
                if (c == 0)      Y[r] = sigmoidf(acc + b2[r]);       // h2 post-act
                else if (!isg)   Y[c * H + r] = acc;                 // raw jacobian col
                else             g2[r] = sigmoidf(acc + bg2[r]);     // g2 post-act
            }
        }
    }
    __threadfence();
    __syncthreads();
    if (tid == 0) release_add(&ready2[c]);

    // ---- Stage 3 ----
    if (!isg) {
        if (tid == 0) {
            acquire_wait(&ready2[0], NRB);
            if (c) acquire_wait(&ready2[c], NRB);
        }
        __syncthreads();
        if (tid < 128) ((float4*)h1s)[tid] = ((const float4*)Y)[tid];           // h2
        else if (c)    ((float4*)rawv)[tid - 128] = ((const float4*)(Y + c * H))[tid - 128];
        __syncthreads();
        if (tid < 128) {
            float4 h = ((const float4*)h1s)[tid];
            float4 bvv;
            if (c == 0) bvv = h;
            else {
                float4 rw = ((const float4*)rawv)[tid];
                bvv = make_float4(h.x*(1.f-h.x)*rw.x, h.y*(1.f-h.y)*rw.y,
                                  h.z*(1.f-h.z)*rw.z, h.w*(1.f-h.w)*rw.w);
            }
            ((float4*)b1s)[tid] = bvv;
        }
        __syncthreads();
        const float4* bvp = (const float4*)b1s;
        float4 v0 = bvp[lane], v1 = bvp[lane + 64];
        int r0 = rb * 64 + wv * 16;
        #pragma unroll 8
        for (int i = 0; i < 16; ++i) {
            int r = r0 + i;
            const float4* wr = (const float4*)W3 + (size_t)r * (H / 4);
            float acc = dot4(wr[lane], v0) + dot4(wr[lane + 64], v1);
            #pragma unroll
            for (int m = 32; m > 0; m >>= 1) acc += __shfl_xor(acc, m, 64);
            if (lane == 0) {
                if (c == 0) Z[r] = sigmoidf(acc + b3[r]);            // h3 post-act
                else        Z[c * H + r] = acc;
            }
        }
        __threadfence();
        __syncthreads();
        if (tid == 0) release_add(&ready3[c]);
    } else if (rb == 0) {
        if (tid == 0) acquire_wait(&ready2[33], NRB);
        __syncthreads();
        if (tid < 128) ((float4*)h1s)[tid] = ((const float4*)g2)[tid];
        __syncthreads();
        const float4* bvp = (const float4*)h1s;
        float4 v0 = bvp[lane], v1 = bvp[lane + 64];
        #pragma unroll
        for (int i = 0; i < 8; ++i) {
            int r = wv * 8 + i;
            const float4* wr = (const float4*)Wg3 + (size_t)r * (H / 4);
            float acc = dot4(wr[lane], v0) + dot4(wr[lane + 64], v1);
            #pragma unroll
            for (int m = 32; m > 0; m >>= 1) acc += __shfl_xor(acc, m, 64);
            if (lane == 0) gvec[r] = acc + bg3[r];
        }
        __threadfence();
        __syncthreads();
    }

    // ---- Stage 4: 66 rows of U[:,c] ----
    if (!isg) {
        if (tid == 0) {
            acquire_wait(&ready3[0], NRB);
            if (c) acquire_wait(&ready3[c], NRB);
        }
        __syncthreads();
        if (tid < 128) ((float4*)h1s)[tid] = ((const float4*)Z)[tid];           // h3
        else if (c)    ((float4*)rawv)[tid - 128] = ((const float4*)(Z + c * H))[tid - 128];
        __syncthreads();
        if (tid < 128) {
            float4 h = ((const float4*)h1s)[tid];
            float4 bvv;
            if (c == 0) bvv = h;
            else {
                float4 rw = ((const float4*)rawv)[tid];
                bvv = make_float4(h.x*(1.f-h.x)*rw.x, h.y*(1.f-h.y)*rw.y,
                                  h.z*(1.f-h.z)*rw.z, h.w*(1.f-h.w)*rw.w);
            }
            ((float4*)b1s)[tid] = bvv;
        }
        __syncthreads();
        const float4* bvp = (const float4*)b1s;
        float4 v0 = bvp[lane], v1 = bvp[lane + 64];
        for (int i = wv; i < 66; i += 4) {
            int r = rb * 66 + i;       // 0..527
            const float4* wr = (r < NQ) ? ((const float4*)Wd + (size_t)r * (H / 4))
                                        : ((const float4*)Wo + (size_t)(r - NQ) * (H / 4));
            float acc = dot4(wr[lane], v0) + dot4(wr[lane + 64], v1);
            #pragma unroll
            for (int m = 32; m > 0; m >>= 1) acc += __shfl_xor(acc, m, 64);
            if (lane == 0) U[c * NR4 + r] = acc;
        }
    }

    // ---- Fan-in: last block does the assembly ----
    __threadfence();
    __syncthreads();
    if (tid == 0) {
        unsigned old = __hip_atomic_fetch_add(done, 1u, __ATOMIC_ACQ_REL, __HIP_MEMORY_SCOPE_AGENT);
        amLast = (old == NBLK - 1) ? 1 : 0;
    }
    __syncthreads();
    if (!amLast) return;

    if (tid < NQ) {
        ldiag[tid] = __expf(U[tid] + bd[tid]);
        qts[tid]  = q_t[tid];
        qtts[tid] = q_tt[tid];
    }
    for (int r = tid; r < NOFF; r += 256)
        loff[r] = U[NQ + r] + bo[r];
    __syncthreads();
    for (int m = tid; m < NR4; m += 256) {
        float acc = 0.f;
        #pragma unroll
        for (int kk = 0; kk < NQ; ++kk)
            acc += U[(kk + 1) * NR4 + m] * qts[kk];
        vv[m] = (m < NQ) ? ldiag[m] * acc : acc;
    }
    for (int p = tid; p < NQ * NQ; p += 256) {
        int i = p >> 5, j = p & 31;
        Lm[i][j] = (i == j) ? ldiag[i]
                 : (j < i ? loff[i * (i - 1) / 2 + j] : 0.f);
    }
    for (int p = tid; p < NQ * NQ; p += 256) {
        int j = p >> 5, kk = p & 31;
        const float* Uc = U + (kk + 1) * NR4;
        float acc = qts[j] * ldiag[j] * Uc[j];
        for (int i = j + 1; i < NQ; ++i)
            acc += qts[i] * Uc[NQ + i * (i - 1) / 2 + j];
        Fj[j][kk] = acc;
    }
    __syncthreads();
    for (int p = tid; p < NQ * NQ; p += 256) {
        int i = p >> 5, j = p & 31;
        Dq[i][j] = (i == j) ? vv[i]
                 : (j < i ? vv[NQ + i * (i - 1) / 2 + j] : 0.f);
    }
    if (tid < NQ) {
        int kcol = tid;
        float a = 0.f, bsum = 0.f;
        #pragma unroll
        for (int j = 0; j < NQ; ++j) {
            a    += Lm[j][kcol] * qts[j];
            bsum += Lm[j][kcol] * qtts[j];
        }
        LTq[kcol] = a;
        t1s[kcol] = bsum;
    }
    __syncthreads();
    if (tid < NQ) {
        int kcol = tid;
        float a = 0.f;
        #pragma unroll
        for (int j = 0; j < NQ; ++j) a += Dq[j][kcol] * qts[j];
        u2[kcol] = a;
    }
    __syncthreads();
    if (tid < NQ) {
        int i = tid;
        float c1 = 0.f, c2 = 0.f, c3 = 0.f, c4 = 0.f;
        #pragma unroll
        for (int kk = 0; kk < NQ; ++kk) {
            c1 += Lm[i][kk] * t1s[kk];
            c2 += Lm[i][kk] * u2[kk];
            c3 += Dq[i][kk] * LTq[kk];
            c4 += Fj[i][kk] * LTq[kk];
        }
        out[i] = c1 + c2 + 0.5f * c3 - 0.5f * c4 + gvec[i];
    }
}

extern "C" void kernel_launch(void* const* d_in, const int* in_sizes, int n_in,
                              void* d_out, int out_size, void* d_ws, size_t ws_size,
                              hipStream_t stream) {
    const float* q    = (const float*)d_in[0];
    const float* q_t  = (const float*)d_in[1];
    const float* q_tt = (const float*)d_in[2];
    const float* W1   = (const float*)d_in[3];
    const float* b1   = (const float*)d_in[4];
    const float* W2   = (const float*)d_in[5];
    const float* b2   = (const float*)d_in[6];
    const float* W3   = (const float*)d_in[7];
    const float* b3   = (const float*)d_in[8];
    const float* Wd   = (const float*)d_in[9];
    const float* bd   = (const float*)d_in[10];
    const float* Wo   = (const float*)d_in[11];
    const float* bo   = (const float*)d_in[12];
    const float* Wg1  = (const float*)d_in[13];
    const float* bg1  = (const float*)d_in[14];
    const float* Wg2  = (const float*)d_in[15];
    const float* bg2  = (const float*)d_in[16];
    const float* Wg3  = (const float*)d_in[17];
    const float* bg3  = (const float*)d_in[18];

    float* ws = (float*)d_ws;
    float* Y       = ws;                   // 33*512 = 16896
    float* Z       = ws + 16896;           // 33*512 = 16896
    float* g2      = ws + 33792;           // 512
    float* gvec    = ws + 34304;           // 32
    float* U       = ws + 34336;           // 33*528 = 17424
    unsigned* ready2 = (unsigned*)(ws + 51760);   // 34
    unsigned* ready3 = (unsigned*)(ws + 51794);   // 33
    unsigned* done   = (unsigned*)(ws + 51827);   // 1
    float* out     = (float*)d_out;

    hipMemsetAsync(ready2, 0, 68 * sizeof(unsigned), stream);
    hipLaunchKernelGGL(fused, dim3(NBLK), dim3(256), 0, stream,
                       q, q_t, q_tt, W1, b1, W2, b2, W3, b3,
                       Wd, bd, Wo, bo, Wg1, bg1, Wg2, bg2, Wg3, bg3,
                       Y, Z, g2, gvec, U, ready2, ready3, done, out);
}

// Round 5
// 151.016 us; speedup vs baseline: 1.7890x; 1.7890x over previous
//
#include <hip/hip_runtime.h>
#include <cmath>

#define NQ 32
#define H 512
#define NOFF 496
#define NR4 528   // NQ + NOFF
#define NBLK 34   // 33 column blocks (k=0 activation, k=1..32 jacobian) + 1 g-net block

__device__ __forceinline__ float sigmoidf(float x) {
    return 1.0f / (1.0f + __expf(-x));
}
__device__ __forceinline__ float dot4(float4 a, float4 b) {
    return a.x * b.x + a.y * b.y + a.z * b.z + a.w * b.w;
}
__device__ __forceinline__ float ldagent(const float* p) {
    return __hip_atomic_load(p, __ATOMIC_RELAXED, __HIP_MEMORY_SCOPE_AGENT);
}
// reduce over the 16-lane k-slice group (lane bits 0..3)
__device__ __forceinline__ float red16(float a) {
    a += __shfl_xor(a, 1, 64);
    a += __shfl_xor(a, 2, 64);
    a += __shfl_xor(a, 4, 64);
    a += __shfl_xor(a, 8, 64);
    return a;
}

// 34 independent blocks (one per column), 1024 threads each. No cross-block
// dependencies; last block (fan-in atomic) assembles tau.
// GEMV layout: 16 lanes per row x 4 rows per wave; each lane holds its
// 32-float k-slice of both B-vectors in registers (loaded from LDS once
// per stage), so the inner loop is pure coalesced W-loads + FMA.
__global__ void __launch_bounds__(1024, 1) fused(
    const float* __restrict__ q, const float* __restrict__ q_t, const float* __restrict__ q_tt,
    const float* __restrict__ W1, const float* __restrict__ b1,
    const float* __restrict__ W2, const float* __restrict__ b2,
    const float* __restrict__ W3, const float* __restrict__ b3,
    const float* __restrict__ Wd, const float* __restrict__ bd,
    const float* __restrict__ Wo, const float* __restrict__ bo,
    const float* __restrict__ Wg1, const float* __restrict__ bg1,
    const float* __restrict__ Wg2, const float* __restrict__ bg2,
    const float* __restrict__ Wg3, const float* __restrict__ bg3,
    float* __restrict__ U, float* __restrict__ gvec,
    unsigned* __restrict__ done, float* __restrict__ out)
{
    const int c = blockIdx.x;          // 0..33
    const int tid = threadIdx.x;       // 0..1023 (16 waves)
    const int lane = tid & 63, w = tid >> 6;
    const int p = lane & 15, rg = lane >> 4;   // k-slice lane, row-in-group
    const bool isg = (c == NBLK - 1);

    __shared__ float qs[NQ];
    __shared__ float hv[H], bvv[H], hv2[H], bv2[H];
    // assembly scratch (last block only)
    __shared__ float ldiag[NQ], loff[NOFF], vv[NR4];
    __shared__ float Lm[NQ][NQ + 1], Dq[NQ][NQ + 1], Fj[NQ][NQ + 1];
    __shared__ float qts[NQ], qtts[NQ], LTq[NQ], t1s[NQ], u2[NQ];
    __shared__ int amLast;

    if (tid < NQ) qs[tid] = q[tid];
    __syncthreads();

    // ---- Stage 1: h1 (or g1) + B1 column ----
    if (tid < H) {
        const float* Wf = isg ? Wg1 : W1;
        const float* bf = isg ? bg1 : b1;
        const float4* wr = (const float4*)(Wf + tid * NQ);
        float acc = 0.f;
        #pragma unroll
        for (int cc = 0; cc < 8; ++cc) {
            float4 wv4 = wr[cc];
            acc += wv4.x * qs[4*cc] + wv4.y * qs[4*cc+1] + wv4.z * qs[4*cc+2] + wv4.w * qs[4*cc+3];
        }
        float h = sigmoidf(acc + bf[tid]);
        hv[tid] = h;
        bvv[tid] = (c == 0 || isg) ? h : h * (1.f - h) * Wf[tid * NQ + (c - 1)];
    }
    __syncthreads();

    // ---- Stage 2: hv/bvv -> hv2/bv2 via W2 (or Wg2) ----
    {
        const float4* hv4 = (const float4*)hv;
        const float4* bv4 = (const float4*)bvv;
        float4 bh[8], bb[8];
        #pragma unroll
        for (int i = 0; i < 8; ++i) { bh[i] = hv4[p + 16*i]; bb[i] = bv4[p + 16*i]; }
        const float4* Wv = (const float4*)(isg ? Wg2 : W2);
        const float* bias = isg ? bg2 : b2;
        #pragma unroll 2
        for (int pass = 0; pass < 8; ++pass) {
            int r = w * 32 + pass * 4 + rg;
            const float4* wr = Wv + (size_t)r * (H / 4);
            float4 wreg[8];
            #pragma unroll
            for (int i = 0; i < 8; ++i) wreg[i] = wr[p + 16*i];
            float aH = 0.f, aB = 0.f;
            #pragma unroll
            for (int i = 0; i < 8; ++i) { aH += dot4(wreg[i], bh[i]); aB += dot4(wreg[i], bb[i]); }
            aH = red16(aH);
            aB = red16(aB);
            if (p == 0) {
                float h2 = sigmoidf(aH + bias[r]);
                hv2[r] = h2;
                bv2[r] = (c == 0 || isg) ? h2 : h2 * (1.f - h2) * aB;
            }
        }
    }
    __syncthreads();

    // ---- Stage 3: hv2/bv2 -> hv/bvv via W3  (g-block: gvec = Wg3@g2 + bg3) ----
    if (!isg) {
        const float4* hv4 = (const float4*)hv2;
        const float4* bv4 = (const float4*)bv2;
        float4 bh[8], bb[8];
        #pragma unroll
        for (int i = 0; i < 8; ++i) { bh[i] = hv4[p + 16*i]; bb[i] = bv4[p + 16*i]; }
        #pragma unroll 2
        for (int pass = 0; pass < 8; ++pass) {
            int r = w * 32 + pass * 4 + rg;
            const float4* wr = (const float4*)W3 + (size_t)r * (H / 4);
            float4 wreg[8];
            #pragma unroll
            for (int i = 0; i < 8; ++i) wreg[i] = wr[p + 16*i];
            float aH = 0.f, aB = 0.f;
            #pragma unroll
            for (int i = 0; i < 8; ++i) { aH += dot4(wreg[i], bh[i]); aB += dot4(wreg[i], bb[i]); }
            aH = red16(aH);
            aB = red16(aB);
            if (p == 0) {
                float h3 = sigmoidf(aH + b3[r]);
                hv[r] = h3;
                bvv[r] = (c == 0) ? h3 : h3 * (1.f - h3) * aB;
            }
        }
    } else {
        const float4* hv4 = (const float4*)hv2;
        float4 bh[8];
        #pragma unroll
        for (int i = 0; i < 8; ++i) bh[i] = hv4[p + 16*i];
        if (w < 8) {
            int r = w * 4 + rg;   // 0..31
            const float4* wr = (const float4*)Wg3 + (size_t)r * (H / 4);
            float4 wreg[8];
            #pragma unroll
            for (int i = 0; i < 8; ++i) wreg[i] = wr[p + 16*i];
            float aH = 0.f;
            #pragma unroll
            for (int i = 0; i < 8; ++i) aH += dot4(wreg[i], bh[i]);
            aH = red16(aH);
            if (p == 0) gvec[r] = aH + bg3[r];
        }
    }
    __syncthreads();

    // ---- Stage 4: U[:,c] = [Wd;Wo] @ bvv  (528 rows) ----
    if (!isg) {
        const float4* bv4 = (const float4*)bvv;
        float4 bb[8];
        #pragma unroll
        for (int i = 0; i < 8; ++i) bb[i] = bv4[p + 16*i];
        #pragma unroll 2
        for (int pass = 0; pass < 9; ++pass) {
            int r = pass * 64 + w * 4 + rg;
            if (r < NR4) {
                const float4* wr = (r < NQ) ? ((const float4*)Wd + (size_t)r * (H / 4))
                                            : ((const float4*)Wo + (size_t)(r - NQ) * (H / 4));
                float4 wreg[8];
                #pragma unroll
                for (int i = 0; i < 8; ++i) wreg[i] = wr[p + 16*i];
                float aB = 0.f;
                #pragma unroll
                for (int i = 0; i < 8; ++i) aB += dot4(wreg[i], bb[i]);
                aB = red16(aB);
                if (p == 0) U[c * NR4 + r] = aB;
            }
        }
    }

    // ---- Fan-in: last block does the assembly ----
    __threadfence();
    __syncthreads();
    if (tid == 0) {
        unsigned old = __hip_atomic_fetch_add(done, 1u, __ATOMIC_ACQ_REL, __HIP_MEMORY_SCOPE_AGENT);
        amLast = (old == NBLK - 1) ? 1 : 0;
    }
    __syncthreads();
    if (!amLast) return;

    // ---- Assembly (one block, 1024 threads) ----
    if (tid < NQ) {
        ldiag[tid] = __expf(ldagent(&U[tid]) + bd[tid]);
        qts[tid]  = q_t[tid];
        qtts[tid] = q_tt[tid];
    }
    for (int r = tid; r < NOFF; r += 1024)
        loff[r] = ldagent(&U[NQ + r]) + bo[r];
    __syncthreads();
    for (int m = tid; m < NR4; m += 1024) {
        float acc = 0.f;
        #pragma unroll
        for (int kk = 0; kk < NQ; ++kk)
            acc += ldagent(&U[(kk + 1) * NR4 + m]) * qts[kk];
        vv[m] = (m < NQ) ? ldiag[m] * acc : acc;
    }
    for (int pp = tid; pp < NQ * NQ; pp += 1024) {
        int i = pp >> 5, j = pp & 31;
        Lm[i][j] = (i == j) ? ldiag[i]
                 : (j < i ? loff[i * (i - 1) / 2 + j] : 0.f);
    }
    for (int pp = tid; pp < NQ * NQ; pp += 1024) {
        int j = pp >> 5, kk = pp & 31;
        const float* Uc = U + (kk + 1) * NR4;
        float acc = qts[j] * ldiag[j] * ldagent(&Uc[j]);
        for (int i = j + 1; i < NQ; ++i)
            acc += qts[i] * ldagent(&Uc[NQ + i * (i - 1) / 2 + j]);
        Fj[j][kk] = acc;
    }
    __syncthreads();
    for (int pp = tid; pp < NQ * NQ; pp += 1024) {
        int i = pp >> 5, j = pp & 31;
        Dq[i][j] = (i == j) ? vv[i]
                 : (j < i ? vv[NQ + i * (i - 1) / 2 + j] : 0.f);
    }
    if (tid < NQ) {
        int kcol = tid;
        float a = 0.f, bsum = 0.f;
        #pragma unroll
        for (int j = 0; j < NQ; ++j) {
            a    += Lm[j][kcol] * qts[j];
            bsum += Lm[j][kcol] * qtts[j];
        }
        LTq[kcol] = a;
        t1s[kcol] = bsum;
    }
    __syncthreads();
    if (tid < NQ) {
        int kcol = tid;
        float a = 0.f;
        #pragma unroll
        for (int j = 0; j < NQ; ++j) a += Dq[j][kcol] * qts[j];
        u2[kcol] = a;
    }
    __syncthreads();
    if (tid < NQ) {
        int i = tid;
        float c1 = 0.f, c2 = 0.f, c3 = 0.f, c4 = 0.f;
        #pragma unroll
        for (int kk = 0; kk < NQ; ++kk) {
            c1 += Lm[i][kk] * t1s[kk];
            c2 += Lm[i][kk] * u2[kk];
            c3 += Dq[i][kk] * LTq[kk];
            c4 += Fj[i][kk] * LTq[kk];
        }
        out[i] = c1 + c2 + 0.5f * c3 - 0.5f * c4 + ldagent(&gvec[i]);
    }
}

extern "C" void kernel_launch(void* const* d_in, const int* in_sizes, int n_in,
                              void* d_out, int out_size, void* d_ws, size_t ws_size,
                              hipStream_t stream) {
    const float* q    = (const float*)d_in[0];
    const float* q_t  = (const float*)d_in[1];
    const float* q_tt = (const float*)d_in[2];
    const float* W1   = (const float*)d_in[3];
    const float* b1   = (const float*)d_in[4];
    const float* W2   = (const float*)d_in[5];
    const float* b2   = (const float*)d_in[6];
    const float* W3   = (const float*)d_in[7];
    const float* b3   = (const float*)d_in[8];
    const float* Wd   = (const float*)d_in[9];
    const float* bd   = (const float*)d_in[10];
    const float* Wo   = (const float*)d_in[11];
    const float* bo   = (const float*)d_in[12];
    const float* Wg1  = (const float*)d_in[13];
    const float* bg1  = (const float*)d_in[14];
    const float* Wg2  = (const float*)d_in[15];
    const float* bg2  = (const float*)d_in[16];
    const float* Wg3  = (const float*)d_in[17];
    const float* bg3  = (const float*)d_in[18];

    float* ws = (float*)d_ws;
    float* U       = ws;                   // 33*528 = 17424 (col-major)
    float* gvec    = ws + 17424;           // 32
    unsigned* done = (unsigned*)(ws + 17456);
    float* out     = (float*)d_out;

    hipMemsetAsync(done, 0, sizeof(unsigned), stream);
    hipLaunchKernelGGL(fused, dim3(NBLK), dim3(1024), 0, stream,
                       q, q_t, q_tt, W1, b1, W2, b2, W3, b3,
                       Wd, bd, Wo, bo, Wg1, bg1, Wg2, bg2, Wg3, bg3,
                       U, gvec, done, out);
}